// Round 3
// baseline (3385.995 us; speedup 1.0000x reference)
//
#include <hip/hip_runtime.h>

#define HW 16384
#define CH 256

// ---------------- depthwise 3x3, pad 1, per-channel, float4 quads ----------------
// grid: B*256 blocks (one (b,c) plane), 256 threads; each thread does 16 pixel-quads.
__global__ __launch_bounds__(256) void k_dw(const float* __restrict__ in,
                                            const float* __restrict__ w,
                                            float* __restrict__ out) {
  int bc = blockIdx.x;
  int c = bc & 255;
  float wv[9];
#pragma unroll
  for (int i = 0; i < 9; ++i) wv[i] = w[c * 9 + i];
  const float* ip = in + (size_t)bc * HW;
  float* op = out + (size_t)bc * HW;
  int t = threadIdx.x;
  for (int r = 0; r < 16; ++r) {
    int q4 = r * 256 + t;
    int pix = q4 * 4;
    int y = pix >> 7, x0 = pix & 127;
    float ax = 0.f, ay = 0.f, az = 0.f, aw = 0.f;
#pragma unroll
    for (int dy = 0; dy < 3; ++dy) {
      int yy = y + dy - 1;
      if (yy < 0 || yy > 127) continue;
      const float* row = ip + yy * 128 + x0;
      float4 cv = *(const float4*)row;
      float lf = (x0 > 0) ? row[-1] : 0.f;
      float rt = (x0 < 124) ? row[4] : 0.f;
      float w0 = wv[dy * 3 + 0], w1 = wv[dy * 3 + 1], w2 = wv[dy * 3 + 2];
      ax += w0 * lf   + w1 * cv.x + w2 * cv.y;
      ay += w0 * cv.x + w1 * cv.y + w2 * cv.z;
      az += w0 * cv.y + w1 * cv.z + w2 * cv.w;
      aw += w0 * cv.z + w1 * cv.w + w2 * rt;
    }
    float4 o; o.x = ax; o.y = ay; o.z = az; o.w = aw;
    *(float4*)(op + pix) = o;
  }
}

// ---------------- pointwise 1x1 as GEMM, 128x128 tile, BK=32, reg-prefetch ----------------
// out[m][n] = sum_k Wt[m][k] * T[b][k][n]
// grid (N/128, M/128, B). blockIdx.y>>1 selects out buffer (fused qkv: M=768 -> 3 bufs).
__global__ __launch_bounds__(256, 2) void k_pw(const float* __restrict__ T,
                                               const float* __restrict__ Wt,
                                               float* __restrict__ o0,
                                               float* __restrict__ o1,
                                               float* __restrict__ o2) {
  __shared__ __align__(16) float As[32][128];  // [k][m] transposed
  __shared__ __align__(16) float Bs[32][128];  // [k][n]
  int b = blockIdx.z;
  int n0 = blockIdx.x * 128;
  int gm0 = blockIdx.y * 128;
  int sel = blockIdx.y >> 1;
  float* outp = sel == 0 ? o0 : (sel == 1 ? o1 : o2);
  int lm0 = (blockIdx.y & 1) * 128;
  const float* Tb = T + (size_t)b * CH * HW;
  int t = threadIdx.x;
  int ty = t >> 4, tx = t & 15;
  int arow = t >> 1, acol = (t & 1) * 16;  // A tile: 128 m x 32 k, 16 floats/thread
  int brow = t >> 3, bcol = (t & 7) * 16;  // B tile: 32 k x 128 n, 16 floats/thread
  const float* aptr = Wt + (size_t)(gm0 + arow) * 256 + acol;
  const float* bptr = Tb + (size_t)brow * HW + n0 + bcol;
  float4 ra[4], rb[4];
#pragma unroll
  for (int i = 0; i < 4; ++i) {
    ra[i] = *(const float4*)(aptr + i * 4);
    rb[i] = *(const float4*)(bptr + i * 4);
  }
  float acc[8][8] = {};
  for (int k0 = 0; k0 < 256; k0 += 32) {
#pragma unroll
    for (int i = 0; i < 4; ++i) {
      As[acol + i * 4 + 0][arow] = ra[i].x;  // bank = arow%32: lane pairs share row -> 2-way (free)
      As[acol + i * 4 + 1][arow] = ra[i].y;
      As[acol + i * 4 + 2][arow] = ra[i].z;
      As[acol + i * 4 + 3][arow] = ra[i].w;
      *(float4*)&Bs[brow][bcol + i * 4] = rb[i];
    }
    __syncthreads();
    if (k0 + 32 < 256) {  // T14: issue next-tile loads before compute; latency hides under FMAs
#pragma unroll
      for (int i = 0; i < 4; ++i) {
        ra[i] = *(const float4*)(aptr + k0 + 32 + i * 4);
        rb[i] = *(const float4*)(bptr + (size_t)(k0 + 32) * HW + i * 4);
      }
    }
#pragma unroll
    for (int kk = 0; kk < 32; ++kk) {
      float4 a0 = *(const float4*)&As[kk][ty * 4];        // broadcast over tx
      float4 a1 = *(const float4*)&As[kk][64 + ty * 4];
      float4 b0 = *(const float4*)&Bs[kk][tx * 4];        // slot = tx%8: conflict-free
      float4 b1 = *(const float4*)&Bs[kk][64 + tx * 4];
      float av[8] = {a0.x, a0.y, a0.z, a0.w, a1.x, a1.y, a1.z, a1.w};
      float bv[8] = {b0.x, b0.y, b0.z, b0.w, b1.x, b1.y, b1.z, b1.w};
#pragma unroll
      for (int i = 0; i < 8; ++i)
#pragma unroll
        for (int j = 0; j < 8; ++j) acc[i][j] += av[i] * bv[j];
    }
    __syncthreads();
  }
#pragma unroll
  for (int ih = 0; ih < 2; ++ih)
#pragma unroll
    for (int i = 0; i < 4; ++i) {
      int lrow = lm0 + ih * 64 + ty * 4 + i;
#pragma unroll
      for (int jh = 0; jh < 2; ++jh) {
        float4 o;
        o.x = acc[ih * 4 + i][jh * 4 + 0]; o.y = acc[ih * 4 + i][jh * 4 + 1];
        o.z = acc[ih * 4 + i][jh * 4 + 2]; o.w = acc[ih * 4 + i][jh * 4 + 3];
        *(float4*)(outp + ((size_t)b * CH + lrow) * HW + n0 + jh * 64 + tx * 4) = o;
      }
    }
}

// ---------------- 8x8 max pool: V layout [bh][cell][64] ----------------
__global__ __launch_bounds__(256) void k_pool(const float* __restrict__ src,
                                              float* __restrict__ dst) {
  int idx = blockIdx.x * 256 + threadIdx.x;
  int cell = idx & 255;
  int c = (idx >> 8) & 255;
  int b = idx >> 16;
  int sy = cell >> 4, sx = cell & 15;
  const float* sp = src + ((size_t)b * CH + c) * HW + (sy * 8) * 128 + sx * 8;
  float m = -1e30f;
#pragma unroll
  for (int iy = 0; iy < 8; ++iy) {
    float4 v0 = *(const float4*)(sp + iy * 128);
    float4 v1 = *(const float4*)(sp + iy * 128 + 4);
    m = fmaxf(m, fmaxf(fmaxf(v0.x, v0.y), fmaxf(v0.z, v0.w)));
    m = fmaxf(m, fmaxf(fmaxf(v1.x, v1.y), fmaxf(v1.z, v1.w)));
  }
  int dh = c >> 2, head = c & 3;
  dst[((size_t)(b * 4 + head) * 256 + cell) * 64 + dh] = m;
}

// ---------------- 8x8 max pool, K transposed layout [bh][d][cell] ----------------
__global__ __launch_bounds__(256) void k_poolT(const float* __restrict__ src,
                                               float* __restrict__ dst) {
  int idx = blockIdx.x * 256 + threadIdx.x;
  int cell = idx & 255;
  int c = (idx >> 8) & 255;
  int b = idx >> 16;
  int sy = cell >> 4, sx = cell & 15;
  const float* sp = src + ((size_t)b * CH + c) * HW + (sy * 8) * 128 + sx * 8;
  float m = -1e30f;
#pragma unroll
  for (int iy = 0; iy < 8; ++iy) {
    float4 v0 = *(const float4*)(sp + iy * 128);
    float4 v1 = *(const float4*)(sp + iy * 128 + 4);
    m = fmaxf(m, fmaxf(fmaxf(v0.x, v0.y), fmaxf(v0.z, v0.w)));
    m = fmaxf(m, fmaxf(fmaxf(v1.x, v1.y), fmaxf(v1.z, v1.w)));
  }
  int dh = c >> 2, head = c & 3;
  dst[((size_t)(b * 4 + head) * 64 + dh) * 256 + cell] = m;
}

// ---------------- attention: two register-tiled GEMMs through LDS ----------------
// q: [B][256][HW] planar (ch = dh*4+head); kp: [bh][64 d][256 cell]; vp: [bh][256 cell][64 d]
// Per block: 64 pixels x 256 keys. 256 thr.
// GEMM1 roles: ty pixel-group (4 pix), tx key-group. GEMM2 roles: ty d-group, tx pixel-group.
// LDS = exactly 40960 B -> 4 blocks/CU:
//   u1  [0..4095]    Qs[64 d][64 pix];  P[64 pix][68] overlays u1+rhw (both dead by then)
//   rhw [4096..6143] [64 pix][32]
//   u2  [6144..10239] K-chunk [64 d][64 key] / V-chunk [64 key][64 d]
// rel tables are read straight from global (16 KB, L1-resident) as float4.
__global__ __launch_bounds__(256, 4) void k_attn(
    const float* __restrict__ q, const float* __restrict__ kp,
    const float* __restrict__ vp, const float* __restrict__ relh,
    const float* __restrict__ relw, float* __restrict__ attn_o,
    float* __restrict__ ao) {
  int tile = blockIdx.x, head = blockIdx.y, b = blockIdx.z;
  int t = threadIdx.x;
  int pix0 = tile * 64;
  int bh = b * 4 + head;
  const size_t kvb = (size_t)bh * 16384;

  __shared__ __align__(16) float sm[10240];
  float* u1 = sm;
  float* rhw = sm + 4096;
  float* u2 = sm + 6144;

  int ty = t >> 4, tx = t & 15;

  // --- stage Qs[d][pix] ---
  {
    int dq = t >> 4, f4 = t & 15;
#pragma unroll
    for (int i = 0; i < 4; ++i) {
      int d = i * 16 + dq;
      *(float4*)&u1[d * 64 + f4 * 4] =
          *(const float4*)(q + ((size_t)(b * CH + d * 4 + head)) * HW + pix0 + f4 * 4);
    }
  }
  __syncthreads();

  // --- rel-pos logits: rhw[pix][m] = q[pix] . rel_row(m); tables from global (L1) ---
  {
    int pp = t >> 2, mg = t & 3;
    int pixel = pix0 + pp;
    int y = pixel >> 7, x = pixel & 127;
    int ybase = 15 - (y >> 3), xbase = 15 - (x >> 3);
    const float* rb[8];
#pragma unroll
    for (int mm = 0; mm < 8; ++mm) {
      int m = mg * 8 + mm;
      rb[mm] = (m < 16) ? (relh + (m + ybase) * 64) : (relw + (m - 16 + xbase) * 64);
    }
    float s[8] = {};
#pragma unroll
    for (int dc = 0; dc < 4; ++dc) {
      float qreg[16];
#pragma unroll
      for (int dd = 0; dd < 16; ++dd) qreg[dd] = u1[(dc * 16 + dd) * 64 + pp];
#pragma unroll
      for (int mm = 0; mm < 8; ++mm) {
#pragma unroll
        for (int d4 = 0; d4 < 4; ++d4) {
          float4 rv = *(const float4*)(rb[mm] + dc * 16 + d4 * 4);
          s[mm] += qreg[d4 * 4 + 0] * rv.x + qreg[d4 * 4 + 1] * rv.y +
                   qreg[d4 * 4 + 2] * rv.z + qreg[d4 * 4 + 3] * rv.w;
        }
      }
    }
#pragma unroll
    for (int mm = 0; mm < 8; ++mm) rhw[pp * 32 + mg * 8 + mm] = s[mm];
  }

  // --- GEMM1: L[4 pix][16 key] over 4 key-chunks of 64 ---
  float L[4][16] = {};
#pragma unroll
  for (int qk = 0; qk < 4; ++qk) {
    __syncthreads();
    {
      int dq = t >> 4, f4 = t & 15;
#pragma unroll
      for (int i = 0; i < 4; ++i) {
        int d = i * 16 + dq;
        *(float4*)&u2[d * 64 + f4 * 4] =
            *(const float4*)(kp + kvb + (size_t)d * 256 + qk * 64 + f4 * 4);
      }
    }
    __syncthreads();
#pragma unroll 8
    for (int d = 0; d < 64; ++d) {
      float4 qv = *(const float4*)&u1[d * 64 + ty * 4];   // broadcast over tx
      float4 kv4 = *(const float4*)&u2[d * 64 + tx * 4];  // slot = tx%8: conflict-free
      float qa[4] = {qv.x, qv.y, qv.z, qv.w};
      float ka[4] = {kv4.x, kv4.y, kv4.z, kv4.w};
#pragma unroll
      for (int i = 0; i < 4; ++i)
#pragma unroll
        for (int j = 0; j < 4; ++j) L[i][qk * 4 + j] += qa[i] * ka[j];
    }
  }

  // --- bias + softmax (rows = pixels; reduce over 16 tx lanes) ---
#pragma unroll
  for (int i = 0; i < 4; ++i) {
    int pp = ty * 4 + i;
    float m_ = -1e30f;
#pragma unroll
    for (int qk = 0; qk < 4; ++qk) {
      int hk = qk * 4 + (tx >> 2);
      float gh = rhw[pp * 32 + hk];
#pragma unroll
      for (int j = 0; j < 4; ++j) {
        int wk = (tx * 4 + j) & 15;
        float v = (L[i][qk * 4 + j] + gh + rhw[pp * 32 + 16 + wk]) * 0.125f;
        L[i][qk * 4 + j] = v;
        m_ = fmaxf(m_, v);
      }
    }
    m_ = fmaxf(m_, __shfl_xor(m_, 1));
    m_ = fmaxf(m_, __shfl_xor(m_, 2));
    m_ = fmaxf(m_, __shfl_xor(m_, 4));
    m_ = fmaxf(m_, __shfl_xor(m_, 8));
    float s_ = 0.f;
#pragma unroll
    for (int k2 = 0; k2 < 16; ++k2) {
      float e = __expf(L[i][k2] - m_);
      L[i][k2] = e;
      s_ += e;
    }
    s_ += __shfl_xor(s_, 1);
    s_ += __shfl_xor(s_, 2);
    s_ += __shfl_xor(s_, 4);
    s_ += __shfl_xor(s_, 8);
    float inv = 1.f / s_;
#pragma unroll
    for (int k2 = 0; k2 < 16; ++k2) L[i][k2] *= inv;
  }

  // --- attn probs store: lanes 0-15 = consecutive key-float4s -> full 64B lines ---
#pragma unroll
  for (int i = 0; i < 4; ++i) {
    float* arow = attn_o + ((size_t)bh * HW + pix0 + ty * 4 + i) * 256 + tx * 4;
#pragma unroll
    for (int qk = 0; qk < 4; ++qk) {
      float4 o;
      o.x = L[i][qk * 4 + 0]; o.y = L[i][qk * 4 + 1];
      o.z = L[i][qk * 4 + 2]; o.w = L[i][qk * 4 + 3];
      *(float4*)(arow + qk * 64) = o;
    }
  }

  // --- GEMM2: O = P @ V, P re-laid as [pix][68] for float4 write AND read ---
  // write slot = 4ty+tx+17i mod 32 (<=4-way, 4 instrs); read slot = 4tx+17i+kq: 2-way (free)
  float acc2[4][4] = {};
#pragma unroll
  for (int qk = 0; qk < 4; ++qk) {
    __syncthreads();  // GEMM1/softmax done -> u1/rhw dead; previous V chunk consumed
#pragma unroll
    for (int i = 0; i < 4; ++i) {  // stage V chunk [64 key][64 d]: straight copy
      int idx = i * 256 + t;
      *(float4*)&u2[idx * 4] = *(const float4*)(vp + kvb + (size_t)qk * 4096 + idx * 4);
    }
#pragma unroll
    for (int i = 0; i < 4; ++i) {  // P[pix][key_local] vector write (GEMM1 roles)
      float4 pv;
      pv.x = L[i][qk * 4 + 0]; pv.y = L[i][qk * 4 + 1];
      pv.z = L[i][qk * 4 + 2]; pv.w = L[i][qk * 4 + 3];
      *(float4*)&u1[(ty * 4 + i) * 68 + tx * 4] = pv;
    }
    __syncthreads();
    // process keys in pairs: 2 P-float4s + 2 V-rows live at a time (keeps VGPR under 128)
#pragma unroll
    for (int kq = 0; kq < 16; ++kq) {
#pragma unroll
      for (int jp = 0; jp < 2; ++jp) {
        float4 v0 = *(const float4*)&u2[(kq * 4 + jp * 2 + 0) * 64 + ty * 4];
        float4 v1 = *(const float4*)&u2[(kq * 4 + jp * 2 + 1) * 64 + ty * 4];
        float va0[4] = {v0.x, v0.y, v0.z, v0.w};
        float va1[4] = {v1.x, v1.y, v1.z, v1.w};
#pragma unroll
        for (int i = 0; i < 4; ++i) {
          float p0 = u1[(tx * 4 + i) * 68 + kq * 4 + jp * 2 + 0];
          float p1 = u1[(tx * 4 + i) * 68 + kq * 4 + jp * 2 + 1];
#pragma unroll
          for (int dd = 0; dd < 4; ++dd)
            acc2[dd][i] += p0 * va0[dd] + p1 * va1[dd];
        }
      }
    }
  }

  // --- ao store: float4 over 4 consecutive pixels, lanes 0-15 contiguous 256B ---
#pragma unroll
  for (int dd = 0; dd < 4; ++dd) {
    int ch = (ty * 4 + dd) * 4 + head;
    float4 o;
    o.x = acc2[dd][0]; o.y = acc2[dd][1]; o.z = acc2[dd][2]; o.w = acc2[dd][3];
    *(float4*)(ao + ((size_t)b * CH + ch) * HW + pix0 + tx * 4) = o;
  }
}

extern "C" void kernel_launch(void* const* d_in, const int* in_sizes, int n_in,
                              void* d_out, int out_size, void* d_ws, size_t ws_size,
                              hipStream_t stream) {
  const float* x   = (const float*)d_in[0];
  const float* dw1 = (const float*)d_in[1];
  const float* pw1 = (const float*)d_in[2];
  const float* krw = (const float*)d_in[3];
  const float* krh = (const float*)d_in[4];
  const float* dw2 = (const float*)d_in[5];
  const float* pw2 = (const float*)d_in[6];

  float* out = (float*)d_out;                      // [B][256][HW], 16,777,216
  float* attnbuf = out + (size_t)16777216;         // [B*4][HW][256], 67,108,864

  // scratch inside d_out's attn region (dead until k_attn writes it):
  float* t1    = attnbuf;                          // dw1 out          (16.7M)
  float* kfull = attnbuf + (size_t)16777216;       // k full-res       (16.7M)
  float* vfull = attnbuf + (size_t)33554432;       // v full-res       (16.7M)
  // d_ws (f32): q/t2 (16,777,216) + kp (262,144) + vp (262,144)
  float* qb = (float*)d_ws;
  float* kp = qb + (size_t)16777216;               // [bh][64 d][256 cell]
  float* vp = kp + (size_t)262144;                 // [bh][256 cell][64 d]
  float* t2 = qb;                                  // reuse q region after attn

  dim3 b256(256);
  k_dw<<<dim3(1024), b256, 0, stream>>>(x, dw1, t1);
  // fused q/k/v pointwise: M=768 -> grid y=6; y>>1 selects {q,k,v} buffer
  k_pw<<<dim3(128, 6, 4), b256, 0, stream>>>(t1, pw1, qb, kfull, vfull);
  k_poolT<<<dim3(1024), b256, 0, stream>>>(kfull, kp);
  k_pool<<<dim3(1024), b256, 0, stream>>>(vfull, vp);
  k_attn<<<dim3(256, 4, 4), b256, 0, stream>>>(qb, kp, vp, krh, krw, attnbuf, out);
  k_dw<<<dim3(1024), b256, 0, stream>>>(out, dw2, t2);
  k_pw<<<dim3(128, 2, 4), b256, 0, stream>>>(t2, pw2, out, out, out);
}

// Round 4
// 1270.052 us; speedup vs baseline: 2.6660x; 2.6660x over previous
//
#include <hip/hip_runtime.h>

#define HW 16384
#define CH 256

// ---------------- depthwise 3x3, pad 1, per-channel, float4 quads ----------------
// grid: B*256 blocks (one (b,c) plane), 256 threads; each thread does 16 pixel-quads.
__global__ __launch_bounds__(256) void k_dw(const float* __restrict__ in,
                                            const float* __restrict__ w,
                                            float* __restrict__ out) {
  int bc = blockIdx.x;
  int c = bc & 255;
  float wv[9];
#pragma unroll
  for (int i = 0; i < 9; ++i) wv[i] = w[c * 9 + i];
  const float* ip = in + (size_t)bc * HW;
  float* op = out + (size_t)bc * HW;
  int t = threadIdx.x;
  for (int r = 0; r < 16; ++r) {
    int q4 = r * 256 + t;
    int pix = q4 * 4;
    int y = pix >> 7, x0 = pix & 127;
    float ax = 0.f, ay = 0.f, az = 0.f, aw = 0.f;
#pragma unroll
    for (int dy = 0; dy < 3; ++dy) {
      int yy = y + dy - 1;
      if (yy < 0 || yy > 127) continue;
      const float* row = ip + yy * 128 + x0;
      float4 cv = *(const float4*)row;
      float lf = (x0 > 0) ? row[-1] : 0.f;
      float rt = (x0 < 124) ? row[4] : 0.f;
      float w0 = wv[dy * 3 + 0], w1 = wv[dy * 3 + 1], w2 = wv[dy * 3 + 2];
      ax += w0 * lf   + w1 * cv.x + w2 * cv.y;
      ay += w0 * cv.x + w1 * cv.y + w2 * cv.z;
      az += w0 * cv.y + w1 * cv.z + w2 * cv.w;
      aw += w0 * cv.z + w1 * cv.w + w2 * rt;
    }
    float4 o; o.x = ax; o.y = ay; o.z = az; o.w = aw;
    *(float4*)(op + pix) = o;
  }
}

// ---------------- pointwise 1x1 as GEMM, 128x128 tile, BK=32, reg-prefetch ----------------
// out[m][n] = sum_k Wt[m][k] * T[b][k][n]
// grid (N/128, M/128, B). blockIdx.y>>1 selects out buffer (fused qkv: M=768 -> 3 bufs).
__global__ __launch_bounds__(256, 2) void k_pw(const float* __restrict__ T,
                                               const float* __restrict__ Wt,
                                               float* __restrict__ o0,
                                               float* __restrict__ o1,
                                               float* __restrict__ o2) {
  __shared__ __align__(16) float As[32][128];  // [k][m] transposed
  __shared__ __align__(16) float Bs[32][128];  // [k][n]
  int b = blockIdx.z;
  int n0 = blockIdx.x * 128;
  int gm0 = blockIdx.y * 128;
  int sel = blockIdx.y >> 1;
  float* outp = sel == 0 ? o0 : (sel == 1 ? o1 : o2);
  int lm0 = (blockIdx.y & 1) * 128;
  const float* Tb = T + (size_t)b * CH * HW;
  int t = threadIdx.x;
  int ty = t >> 4, tx = t & 15;
  int arow = t >> 1, acol = (t & 1) * 16;  // A tile: 128 m x 32 k, 16 floats/thread
  int brow = t >> 3, bcol = (t & 7) * 16;  // B tile: 32 k x 128 n, 16 floats/thread
  const float* aptr = Wt + (size_t)(gm0 + arow) * 256 + acol;
  const float* bptr = Tb + (size_t)brow * HW + n0 + bcol;
  float4 ra[4], rb[4];
#pragma unroll
  for (int i = 0; i < 4; ++i) {
    ra[i] = *(const float4*)(aptr + i * 4);
    rb[i] = *(const float4*)(bptr + i * 4);
  }
  float acc[8][8] = {};
  for (int k0 = 0; k0 < 256; k0 += 32) {
#pragma unroll
    for (int i = 0; i < 4; ++i) {
      As[acol + i * 4 + 0][arow] = ra[i].x;  // bank = arow%32: lane pairs share row -> 2-way (free)
      As[acol + i * 4 + 1][arow] = ra[i].y;
      As[acol + i * 4 + 2][arow] = ra[i].z;
      As[acol + i * 4 + 3][arow] = ra[i].w;
      *(float4*)&Bs[brow][bcol + i * 4] = rb[i];
    }
    __syncthreads();
    if (k0 + 32 < 256) {  // T14: issue next-tile loads before compute; latency hides under FMAs
#pragma unroll
      for (int i = 0; i < 4; ++i) {
        ra[i] = *(const float4*)(aptr + k0 + 32 + i * 4);
        rb[i] = *(const float4*)(bptr + (size_t)(k0 + 32) * HW + i * 4);
      }
    }
#pragma unroll
    for (int kk = 0; kk < 32; ++kk) {
      float4 a0 = *(const float4*)&As[kk][ty * 4];        // broadcast over tx
      float4 a1 = *(const float4*)&As[kk][64 + ty * 4];
      float4 b0 = *(const float4*)&Bs[kk][tx * 4];        // slot = tx%8: conflict-free
      float4 b1 = *(const float4*)&Bs[kk][64 + tx * 4];
      float av[8] = {a0.x, a0.y, a0.z, a0.w, a1.x, a1.y, a1.z, a1.w};
      float bv[8] = {b0.x, b0.y, b0.z, b0.w, b1.x, b1.y, b1.z, b1.w};
#pragma unroll
      for (int i = 0; i < 8; ++i)
#pragma unroll
        for (int j = 0; j < 8; ++j) acc[i][j] += av[i] * bv[j];
    }
    __syncthreads();
  }
#pragma unroll
  for (int ih = 0; ih < 2; ++ih)
#pragma unroll
    for (int i = 0; i < 4; ++i) {
      int lrow = lm0 + ih * 64 + ty * 4 + i;
#pragma unroll
      for (int jh = 0; jh < 2; ++jh) {
        float4 o;
        o.x = acc[ih * 4 + i][jh * 4 + 0]; o.y = acc[ih * 4 + i][jh * 4 + 1];
        o.z = acc[ih * 4 + i][jh * 4 + 2]; o.w = acc[ih * 4 + i][jh * 4 + 3];
        *(float4*)(outp + ((size_t)b * CH + lrow) * HW + n0 + jh * 64 + tx * 4) = o;
      }
    }
}

// ---------------- 8x8 max pool: V layout [bh][cell][64] ----------------
__global__ __launch_bounds__(256) void k_pool(const float* __restrict__ src,
                                              float* __restrict__ dst) {
  int idx = blockIdx.x * 256 + threadIdx.x;
  int cell = idx & 255;
  int c = (idx >> 8) & 255;
  int b = idx >> 16;
  int sy = cell >> 4, sx = cell & 15;
  const float* sp = src + ((size_t)b * CH + c) * HW + (sy * 8) * 128 + sx * 8;
  float m = -1e30f;
#pragma unroll
  for (int iy = 0; iy < 8; ++iy) {
    float4 v0 = *(const float4*)(sp + iy * 128);
    float4 v1 = *(const float4*)(sp + iy * 128 + 4);
    m = fmaxf(m, fmaxf(fmaxf(v0.x, v0.y), fmaxf(v0.z, v0.w)));
    m = fmaxf(m, fmaxf(fmaxf(v1.x, v1.y), fmaxf(v1.z, v1.w)));
  }
  int dh = c >> 2, head = c & 3;
  dst[((size_t)(b * 4 + head) * 256 + cell) * 64 + dh] = m;
}

// ---------------- 8x8 max pool, K transposed layout [bh][d][cell] ----------------
__global__ __launch_bounds__(256) void k_poolT(const float* __restrict__ src,
                                               float* __restrict__ dst) {
  int idx = blockIdx.x * 256 + threadIdx.x;
  int cell = idx & 255;
  int c = (idx >> 8) & 255;
  int b = idx >> 16;
  int sy = cell >> 4, sx = cell & 15;
  const float* sp = src + ((size_t)b * CH + c) * HW + (sy * 8) * 128 + sx * 8;
  float m = -1e30f;
#pragma unroll
  for (int iy = 0; iy < 8; ++iy) {
    float4 v0 = *(const float4*)(sp + iy * 128);
    float4 v1 = *(const float4*)(sp + iy * 128 + 4);
    m = fmaxf(m, fmaxf(fmaxf(v0.x, v0.y), fmaxf(v0.z, v0.w)));
    m = fmaxf(m, fmaxf(fmaxf(v1.x, v1.y), fmaxf(v1.z, v1.w)));
  }
  int dh = c >> 2, head = c & 3;
  dst[((size_t)(b * 4 + head) * 64 + dh) * 256 + cell] = m;
}

// ---------------- attention: two register-tiled GEMMs through LDS ----------------
// q: [B][256][HW] planar (ch = dh*4+head); kp: [bh][64 d][256 cell]; vp: [bh][256 cell][64 d]
// Per block: 64 pixels x 256 keys. 256 thr.
// GEMM1 roles: pix = 4*ty+i, key = 4*tx+j. GEMM2 roles: pix = 16*i+tx, d = 4*ty+dd.
// LDS = 40960 B:
//   u1  [0..4095]    Qs[64 d][64 pix];  P[64 pix][68] overlays u1+rhw (both dead by then)
//   rhw [4096..6143] [64 pix][32]
//   u2  [6144..10239] K-chunk [64 d][64 key] / V-chunk [64 key][64 d]
// rel tables read straight from global (16 KB, L1-resident) as float4.
__global__ __launch_bounds__(256, 3) void k_attn(
    const float* __restrict__ q, const float* __restrict__ kp,
    const float* __restrict__ vp, const float* __restrict__ relh,
    const float* __restrict__ relw, float* __restrict__ attn_o,
    float* __restrict__ ao) {
  int tile = blockIdx.x, head = blockIdx.y, b = blockIdx.z;
  int t = threadIdx.x;
  int pix0 = tile * 64;
  int bh = b * 4 + head;
  const size_t kvb = (size_t)bh * 16384;

  __shared__ __align__(16) float sm[10240];
  float* u1 = sm;
  float* rhw = sm + 4096;
  float* u2 = sm + 6144;

  int ty = t >> 4, tx = t & 15;

  // --- stage Qs[d][pix] ---
  {
    int dq = t >> 4, f4 = t & 15;
#pragma unroll
    for (int i = 0; i < 4; ++i) {
      int d = i * 16 + dq;
      *(float4*)&u1[d * 64 + f4 * 4] =
          *(const float4*)(q + ((size_t)(b * CH + d * 4 + head)) * HW + pix0 + f4 * 4);
    }
  }
  __syncthreads();

  // --- rel-pos logits: rhw[pix][m] = q[pix] . rel_row(m); tables from global (L1) ---
  {
    int pp = t >> 2, mg = t & 3;
    int pixel = pix0 + pp;
    int y = pixel >> 7, x = pixel & 127;
    int ybase = 15 - (y >> 3), xbase = 15 - (x >> 3);
    const float* rb[8];
#pragma unroll
    for (int mm = 0; mm < 8; ++mm) {
      int m = mg * 8 + mm;
      rb[mm] = (m < 16) ? (relh + (m + ybase) * 64) : (relw + (m - 16 + xbase) * 64);
    }
    float s[8] = {};
#pragma unroll
    for (int dc = 0; dc < 4; ++dc) {
      float qreg[16];
#pragma unroll
      for (int dd = 0; dd < 16; ++dd) qreg[dd] = u1[(dc * 16 + dd) * 64 + pp];
#pragma unroll
      for (int mm = 0; mm < 8; ++mm) {
#pragma unroll
        for (int d4 = 0; d4 < 4; ++d4) {
          float4 rv = *(const float4*)(rb[mm] + dc * 16 + d4 * 4);
          s[mm] += qreg[d4 * 4 + 0] * rv.x + qreg[d4 * 4 + 1] * rv.y +
                   qreg[d4 * 4 + 2] * rv.z + qreg[d4 * 4 + 3] * rv.w;
        }
      }
    }
#pragma unroll
    for (int mm = 0; mm < 8; ++mm) rhw[pp * 32 + mg * 8 + mm] = s[mm];
  }

  // --- GEMM1: L[4 pix][16 key] over 4 key-chunks of 64 ---
  float L[4][16] = {};
#pragma unroll
  for (int qk = 0; qk < 4; ++qk) {
    __syncthreads();
    {
      int dq = t >> 4, f4 = t & 15;
#pragma unroll
      for (int i = 0; i < 4; ++i) {
        int d = i * 16 + dq;
        *(float4*)&u2[d * 64 + f4 * 4] =
            *(const float4*)(kp + kvb + (size_t)d * 256 + qk * 64 + f4 * 4);
      }
    }
    __syncthreads();
#pragma unroll 8
    for (int d = 0; d < 64; ++d) {
      float4 qv = *(const float4*)&u1[d * 64 + ty * 4];   // broadcast over tx
      float4 kv4 = *(const float4*)&u2[d * 64 + tx * 4];  // slot = tx%8: conflict-free
      float qa[4] = {qv.x, qv.y, qv.z, qv.w};
      float ka[4] = {kv4.x, kv4.y, kv4.z, kv4.w};
#pragma unroll
      for (int i = 0; i < 4; ++i)
#pragma unroll
        for (int j = 0; j < 4; ++j) L[i][qk * 4 + j] += qa[i] * ka[j];
    }
  }

  // --- bias + softmax (rows = pixels; reduce over 16 tx lanes) ---
#pragma unroll
  for (int i = 0; i < 4; ++i) {
    int pp = ty * 4 + i;
    float m_ = -1e30f;
#pragma unroll
    for (int qk = 0; qk < 4; ++qk) {
      int hk = qk * 4 + (tx >> 2);
      float gh = rhw[pp * 32 + hk];
#pragma unroll
      for (int j = 0; j < 4; ++j) {
        int wk = (tx * 4 + j) & 15;
        float v = (L[i][qk * 4 + j] + gh + rhw[pp * 32 + 16 + wk]) * 0.125f;
        L[i][qk * 4 + j] = v;
        m_ = fmaxf(m_, v);
      }
    }
    m_ = fmaxf(m_, __shfl_xor(m_, 1));
    m_ = fmaxf(m_, __shfl_xor(m_, 2));
    m_ = fmaxf(m_, __shfl_xor(m_, 4));
    m_ = fmaxf(m_, __shfl_xor(m_, 8));
    float s_ = 0.f;
#pragma unroll
    for (int k2 = 0; k2 < 16; ++k2) {
      float e = __expf(L[i][k2] - m_);
      L[i][k2] = e;
      s_ += e;
    }
    s_ += __shfl_xor(s_, 1);
    s_ += __shfl_xor(s_, 2);
    s_ += __shfl_xor(s_, 4);
    s_ += __shfl_xor(s_, 8);
    float inv = 1.f / s_;
#pragma unroll
    for (int k2 = 0; k2 < 16; ++k2) L[i][k2] *= inv;
  }

  // --- attn probs store: lanes 0-15 = consecutive key-float4s -> full 64B lines ---
#pragma unroll
  for (int i = 0; i < 4; ++i) {
    float* arow = attn_o + ((size_t)bh * HW + pix0 + ty * 4 + i) * 256 + tx * 4;
#pragma unroll
    for (int qk = 0; qk < 4; ++qk) {
      float4 o;
      o.x = L[i][qk * 4 + 0]; o.y = L[i][qk * 4 + 1];
      o.z = L[i][qk * 4 + 2]; o.w = L[i][qk * 4 + 3];
      *(float4*)(arow + qk * 64) = o;
    }
  }

  // --- GEMM2: O = P @ V; P[pix][68] (17 slots/row) ---
  // P-read rows are 16*i+tx -> slot = 17*(16i+tx)+kq = tx+kq (mod 8): 2-way, free.
  // V-read broadcast over tx (4 distinct addrs/wave). P-write: 4 b128/thread.
  float acc2[4][4] = {};  // [i: pix-block 16i+tx][dd: d = 4ty+dd]
#pragma unroll
  for (int qk = 0; qk < 4; ++qk) {
    __syncthreads();  // GEMM1/softmax done -> u1/rhw dead; previous V chunk consumed
#pragma unroll
    for (int i = 0; i < 4; ++i) {  // stage V chunk [64 key][64 d]: straight copy
      int idx = i * 256 + t;
      *(float4*)&u2[idx * 4] = *(const float4*)(vp + kvb + (size_t)qk * 4096 + idx * 4);
    }
#pragma unroll
    for (int i = 0; i < 4; ++i) {  // P write (GEMM1 roles): row 4ty+i, cols 4tx..4tx+3
      float4 pv;
      pv.x = L[i][qk * 4 + 0]; pv.y = L[i][qk * 4 + 1];
      pv.z = L[i][qk * 4 + 2]; pv.w = L[i][qk * 4 + 3];
      *(float4*)&u1[(ty * 4 + i) * 68 + tx * 4] = pv;
    }
    __syncthreads();
#pragma unroll
    for (int kq = 0; kq < 16; ++kq) {
      float4 pa0 = *(const float4*)&u1[(0 * 16 + tx) * 68 + kq * 4];
      float4 pa1 = *(const float4*)&u1[(1 * 16 + tx) * 68 + kq * 4];
      float4 pa2 = *(const float4*)&u1[(2 * 16 + tx) * 68 + kq * 4];
      float4 pa3 = *(const float4*)&u1[(3 * 16 + tx) * 68 + kq * 4];
      float4 v0 = *(const float4*)&u2[(kq * 4 + 0) * 64 + ty * 4];
      float4 v1 = *(const float4*)&u2[(kq * 4 + 1) * 64 + ty * 4];
      float4 v2 = *(const float4*)&u2[(kq * 4 + 2) * 64 + ty * 4];
      float4 v3 = *(const float4*)&u2[(kq * 4 + 3) * 64 + ty * 4];
      float pav[4][4] = {{pa0.x, pa0.y, pa0.z, pa0.w},
                         {pa1.x, pa1.y, pa1.z, pa1.w},
                         {pa2.x, pa2.y, pa2.z, pa2.w},
                         {pa3.x, pa3.y, pa3.z, pa3.w}};
      float vvv[4][4] = {{v0.x, v0.y, v0.z, v0.w},
                         {v1.x, v1.y, v1.z, v1.w},
                         {v2.x, v2.y, v2.z, v2.w},
                         {v3.x, v3.y, v3.z, v3.w}};
#pragma unroll
      for (int i = 0; i < 4; ++i)
#pragma unroll
        for (int dd = 0; dd < 4; ++dd)
          acc2[i][dd] += pav[i][0] * vvv[0][dd] + pav[i][1] * vvv[1][dd] +
                         pav[i][2] * vvv[2][dd] + pav[i][3] * vvv[3][dd];
    }
  }

  // --- ao store: pix = pix0 + 16*i + tx -> lanes tx consecutive, 64B segments ---
#pragma unroll
  for (int dd = 0; dd < 4; ++dd) {
    int ch = (ty * 4 + dd) * 4 + head;
    float* base = ao + ((size_t)b * CH + ch) * HW + pix0 + tx;
#pragma unroll
    for (int i = 0; i < 4; ++i) base[i * 16] = acc2[i][dd];
  }
}

extern "C" void kernel_launch(void* const* d_in, const int* in_sizes, int n_in,
                              void* d_out, int out_size, void* d_ws, size_t ws_size,
                              hipStream_t stream) {
  const float* x   = (const float*)d_in[0];
  const float* dw1 = (const float*)d_in[1];
  const float* pw1 = (const float*)d_in[2];
  const float* krw = (const float*)d_in[3];
  const float* krh = (const float*)d_in[4];
  const float* dw2 = (const float*)d_in[5];
  const float* pw2 = (const float*)d_in[6];

  float* out = (float*)d_out;                      // [B][256][HW], 16,777,216
  float* attnbuf = out + (size_t)16777216;         // [B*4][HW][256], 67,108,864

  // scratch inside d_out's attn region (dead until k_attn writes it):
  float* t1    = attnbuf;                          // dw1 out          (16.7M)
  float* kfull = attnbuf + (size_t)16777216;       // k full-res       (16.7M)
  float* vfull = attnbuf + (size_t)33554432;       // v full-res       (16.7M)
  // d_ws (f32): q/t2 (16,777,216) + kp (262,144) + vp (262,144)
  float* qb = (float*)d_ws;
  float* kp = qb + (size_t)16777216;               // [bh][64 d][256 cell]
  float* vp = kp + (size_t)262144;                 // [bh][256 cell][64 d]
  float* t2 = qb;                                  // reuse q region after attn

  dim3 b256(256);
  k_dw<<<dim3(1024), b256, 0, stream>>>(x, dw1, t1);
  // fused q/k/v pointwise: M=768 -> grid y=6; y>>1 selects {q,k,v} buffer
  k_pw<<<dim3(128, 6, 4), b256, 0, stream>>>(t1, pw1, qb, kfull, vfull);
  k_poolT<<<dim3(1024), b256, 0, stream>>>(kfull, kp);
  k_pool<<<dim3(1024), b256, 0, stream>>>(vfull, vp);
  k_attn<<<dim3(256, 4, 4), b256, 0, stream>>>(qb, kp, vp, krh, krw, attnbuf, out);
  k_dw<<<dim3(1024), b256, 0, stream>>>(out, dw2, t2);
  k_pw<<<dim3(128, 2, 4), b256, 0, stream>>>(t2, pw2, out, out, out);
}

// Round 5
// 1154.375 us; speedup vs baseline: 2.9332x; 1.1002x over previous
//
#include <hip/hip_runtime.h>

#define HW 16384
#define CH 256

// ---------------- depthwise 3x3, pad 1, per-channel, float4 quads ----------------
// grid: B*256 blocks (one (b,c) plane), 256 threads; each thread does 16 pixel-quads.
__global__ __launch_bounds__(256) void k_dw(const float* __restrict__ in,
                                            const float* __restrict__ w,
                                            float* __restrict__ out) {
  int bc = blockIdx.x;
  int c = bc & 255;
  float wv[9];
#pragma unroll
  for (int i = 0; i < 9; ++i) wv[i] = w[c * 9 + i];
  const float* ip = in + (size_t)bc * HW;
  float* op = out + (size_t)bc * HW;
  int t = threadIdx.x;
  for (int r = 0; r < 16; ++r) {
    int q4 = r * 256 + t;
    int pix = q4 * 4;
    int y = pix >> 7, x0 = pix & 127;
    float ax = 0.f, ay = 0.f, az = 0.f, aw = 0.f;
#pragma unroll
    for (int dy = 0; dy < 3; ++dy) {
      int yy = y + dy - 1;
      if (yy < 0 || yy > 127) continue;
      const float* row = ip + yy * 128 + x0;
      float4 cv = *(const float4*)row;
      float lf = (x0 > 0) ? row[-1] : 0.f;
      float rt = (x0 < 124) ? row[4] : 0.f;
      float w0 = wv[dy * 3 + 0], w1 = wv[dy * 3 + 1], w2 = wv[dy * 3 + 2];
      ax += w0 * lf   + w1 * cv.x + w2 * cv.y;
      ay += w0 * cv.x + w1 * cv.y + w2 * cv.z;
      az += w0 * cv.y + w1 * cv.z + w2 * cv.w;
      aw += w0 * cv.z + w1 * cv.w + w2 * rt;
    }
    float4 o; o.x = ax; o.y = ay; o.z = az; o.w = aw;
    *(float4*)(op + pix) = o;
  }
}

// ---------------- pointwise 1x1 as GEMM, 128x128 tile, BK=32, reg-prefetch ----------------
// out[m][n] = sum_k Wt[m][k] * T[b][k][n]
// grid (N/128, M/128, B). blockIdx.y>>1 selects out buffer (fused qkv: M=768 -> 3 bufs).
__global__ __launch_bounds__(256, 2) void k_pw(const float* __restrict__ T,
                                               const float* __restrict__ Wt,
                                               float* __restrict__ o0,
                                               float* __restrict__ o1,
                                               float* __restrict__ o2) {
  __shared__ __align__(16) float As[32][128];  // [k][m] transposed
  __shared__ __align__(16) float Bs[32][128];  // [k][n]
  int b = blockIdx.z;
  int n0 = blockIdx.x * 128;
  int gm0 = blockIdx.y * 128;
  int sel = blockIdx.y >> 1;
  float* outp = sel == 0 ? o0 : (sel == 1 ? o1 : o2);
  int lm0 = (blockIdx.y & 1) * 128;
  const float* Tb = T + (size_t)b * CH * HW;
  int t = threadIdx.x;
  int ty = t >> 4, tx = t & 15;
  int arow = t >> 1, acol = (t & 1) * 16;  // A tile: 128 m x 32 k, 16 floats/thread
  int brow = t >> 3, bcol = (t & 7) * 16;  // B tile: 32 k x 128 n, 16 floats/thread
  const float* aptr = Wt + (size_t)(gm0 + arow) * 256 + acol;
  const float* bptr = Tb + (size_t)brow * HW + n0 + bcol;
  float4 ra[4], rb[4];
#pragma unroll
  for (int i = 0; i < 4; ++i) {
    ra[i] = *(const float4*)(aptr + i * 4);
    rb[i] = *(const float4*)(bptr + i * 4);
  }
  float acc[8][8] = {};
  for (int k0 = 0; k0 < 256; k0 += 32) {
#pragma unroll
    for (int i = 0; i < 4; ++i) {
      As[acol + i * 4 + 0][arow] = ra[i].x;  // bank = arow%32: lane pairs share row -> 2-way (free)
      As[acol + i * 4 + 1][arow] = ra[i].y;
      As[acol + i * 4 + 2][arow] = ra[i].z;
      As[acol + i * 4 + 3][arow] = ra[i].w;
      *(float4*)&Bs[brow][bcol + i * 4] = rb[i];
    }
    __syncthreads();
    if (k0 + 32 < 256) {  // T14: issue next-tile loads before compute; latency hides under FMAs
#pragma unroll
      for (int i = 0; i < 4; ++i) {
        ra[i] = *(const float4*)(aptr + k0 + 32 + i * 4);
        rb[i] = *(const float4*)(bptr + (size_t)(k0 + 32) * HW + i * 4);
      }
    }
#pragma unroll
    for (int kk = 0; kk < 32; ++kk) {
      float4 a0 = *(const float4*)&As[kk][ty * 4];        // broadcast over tx
      float4 a1 = *(const float4*)&As[kk][64 + ty * 4];
      float4 b0 = *(const float4*)&Bs[kk][tx * 4];        // slot = tx%8: conflict-free
      float4 b1 = *(const float4*)&Bs[kk][64 + tx * 4];
      float av[8] = {a0.x, a0.y, a0.z, a0.w, a1.x, a1.y, a1.z, a1.w};
      float bv[8] = {b0.x, b0.y, b0.z, b0.w, b1.x, b1.y, b1.z, b1.w};
#pragma unroll
      for (int i = 0; i < 8; ++i)
#pragma unroll
        for (int j = 0; j < 8; ++j) acc[i][j] += av[i] * bv[j];
    }
    __syncthreads();
  }
#pragma unroll
  for (int ih = 0; ih < 2; ++ih)
#pragma unroll
    for (int i = 0; i < 4; ++i) {
      int lrow = lm0 + ih * 64 + ty * 4 + i;
#pragma unroll
      for (int jh = 0; jh < 2; ++jh) {
        float4 o;
        o.x = acc[ih * 4 + i][jh * 4 + 0]; o.y = acc[ih * 4 + i][jh * 4 + 1];
        o.z = acc[ih * 4 + i][jh * 4 + 2]; o.w = acc[ih * 4 + i][jh * 4 + 3];
        *(float4*)(outp + ((size_t)b * CH + lrow) * HW + n0 + jh * 64 + tx * 4) = o;
      }
    }
}

// ---------------- 8x8 max pool: V layout [bh][cell][64] ----------------
__global__ __launch_bounds__(256) void k_pool(const float* __restrict__ src,
                                              float* __restrict__ dst) {
  int idx = blockIdx.x * 256 + threadIdx.x;
  int cell = idx & 255;
  int c = (idx >> 8) & 255;
  int b = idx >> 16;
  int sy = cell >> 4, sx = cell & 15;
  const float* sp = src + ((size_t)b * CH + c) * HW + (sy * 8) * 128 + sx * 8;
  float m = -1e30f;
#pragma unroll
  for (int iy = 0; iy < 8; ++iy) {
    float4 v0 = *(const float4*)(sp + iy * 128);
    float4 v1 = *(const float4*)(sp + iy * 128 + 4);
    m = fmaxf(m, fmaxf(fmaxf(v0.x, v0.y), fmaxf(v0.z, v0.w)));
    m = fmaxf(m, fmaxf(fmaxf(v1.x, v1.y), fmaxf(v1.z, v1.w)));
  }
  int dh = c >> 2, head = c & 3;
  dst[((size_t)(b * 4 + head) * 256 + cell) * 64 + dh] = m;
}

// ---------------- 8x8 max pool, K transposed layout [bh][d][cell] ----------------
__global__ __launch_bounds__(256) void k_poolT(const float* __restrict__ src,
                                               float* __restrict__ dst) {
  int idx = blockIdx.x * 256 + threadIdx.x;
  int cell = idx & 255;
  int c = (idx >> 8) & 255;
  int b = idx >> 16;
  int sy = cell >> 4, sx = cell & 15;
  const float* sp = src + ((size_t)b * CH + c) * HW + (sy * 8) * 128 + sx * 8;
  float m = -1e30f;
#pragma unroll
  for (int iy = 0; iy < 8; ++iy) {
    float4 v0 = *(const float4*)(sp + iy * 128);
    float4 v1 = *(const float4*)(sp + iy * 128 + 4);
    m = fmaxf(m, fmaxf(fmaxf(v0.x, v0.y), fmaxf(v0.z, v0.w)));
    m = fmaxf(m, fmaxf(fmaxf(v1.x, v1.y), fmaxf(v1.z, v1.w)));
  }
  int dh = c >> 2, head = c & 3;
  dst[((size_t)(b * 4 + head) * 64 + dh) * 256 + cell] = m;
}

// ---------------- attention: two register-tiled GEMMs through LDS ----------------
// EXACT round-1 version (measured 315 us, VALUBusy 67%, ideal WRITE_SIZE).
// q: [B][256][HW] planar (ch = dh*4+head); kp: [bh][64 d][256 cell]; vp: [bh][256 cell][64 d]
// Per block: 64 pixels x 256 keys. 256 thr.
// GEMM1 roles: ty=t>>4 pixel-group (4 pix), tx=t&15 key-group (keys qk*64+tx*4+j).
// GEMM2 roles: ty=d-group (4 d), tx=pixel-group (4 pix) -> direct full-line ao stores.
// LDS (40.25KB, 3 blocks/CU):
//   u1: Qs[64 d][64 pix] (GEMM1)  then P_c[64 key][65] bit-swapped cols (GEMM2)
//   u2: relc[2][31][65]  then Ks_c[64 d][64 key] / Vs_c[64 key][64 d]
//   rhw[64 pix][32]
__global__ __launch_bounds__(256, 3) void k_attn(
    const float* __restrict__ q, const float* __restrict__ kp,
    const float* __restrict__ vp, const float* __restrict__ relh,
    const float* __restrict__ relw, float* __restrict__ attn_o,
    float* __restrict__ ao) {
  int tile = blockIdx.x, head = blockIdx.y, b = blockIdx.z;
  int t = threadIdx.x;
  int pix0 = tile * 64;
  int bh = b * 4 + head;
  const size_t kvb = (size_t)bh * 16384;

  __shared__ __align__(16) float sm[10304];
  float* u1 = sm;            // 4160 floats
  float* u2 = sm + 4160;     // 4096 floats
  float* rhw = sm + 8256;    // 2048 floats

  int ty = t >> 4, tx = t & 15;

  // --- stage Qs[d][pix]: lanes 0-15 contiguous 64 floats of one channel row ---
  {
    int dq = t >> 4, f4 = t & 15;
#pragma unroll
    for (int i = 0; i < 4; ++i) {
      int d = i * 16 + dq;
      *(float4*)&u1[d * 64 + f4 * 4] =
          *(const float4*)(q + ((size_t)(b * CH + d * 4 + head)) * HW + pix0 + f4 * 4);
    }
  }
  // --- stage rel tables padded to stride 65 (row-stride != 0 mod 32 banks) ---
  for (int e = t; e < 3968; e += 256) {
    int tab = e >= 1984 ? 1 : 0;
    int e2 = tab ? e - 1984 : e;
    int row = e2 >> 6, d = e2 & 63;
    u2[tab * 2015 + row * 65 + d] = tab ? relw[e2] : relh[e2];
  }
  __syncthreads();

  // --- rel-pos logits: rhw[pix][m] = q[pix] . rel_row(m), m<16 keyed by hk, m>=16 by wk ---
  {
    int pp = t >> 2, mg = t & 3;
    int pixel = pix0 + pp;
    int y = pixel >> 7, x = pixel & 127;
    int ybase = 15 - (y >> 3), xbase = 15 - (x >> 3);
    int roff[8];
#pragma unroll
    for (int mm = 0; mm < 8; ++mm) {
      int m = mg * 8 + mm;
      roff[mm] = (m < 16) ? (m + ybase) * 65 : 2015 + (m - 16 + xbase) * 65;
    }
    float s[8] = {};
#pragma unroll 4
    for (int d = 0; d < 64; ++d) {
      float qv = u1[d * 64 + pp];
#pragma unroll
      for (int mm = 0; mm < 8; ++mm) s[mm] += qv * u2[roff[mm] + d];
    }
#pragma unroll
    for (int mm = 0; mm < 8; ++mm) rhw[pp * 32 + mg * 8 + mm] = s[mm];
  }

  // --- GEMM1: L[4 pix][16 key] over 4 key-chunks of 64 ---
  float L[4][16] = {};
#pragma unroll
  for (int qk = 0; qk < 4; ++qk) {
    __syncthreads();  // relc / previous Ks_c readers done
    {
      int dq = t >> 4, f4 = t & 15;
#pragma unroll
      for (int i = 0; i < 4; ++i) {
        int d = i * 16 + dq;
        *(float4*)&u2[d * 64 + f4 * 4] =
            *(const float4*)(kp + kvb + (size_t)d * 256 + qk * 64 + f4 * 4);
      }
    }
    __syncthreads();
#pragma unroll 8
    for (int d = 0; d < 64; ++d) {
      float4 qv = *(const float4*)&u1[d * 64 + ty * 4];   // broadcast over tx
      float4 kv4 = *(const float4*)&u2[d * 64 + tx * 4];  // slot = tx%8: conflict-free
      float qa[4] = {qv.x, qv.y, qv.z, qv.w};
      float ka[4] = {kv4.x, kv4.y, kv4.z, kv4.w};
#pragma unroll
      for (int i = 0; i < 4; ++i)
#pragma unroll
        for (int j = 0; j < 4; ++j) L[i][qk * 4 + j] += qa[i] * ka[j];
    }
  }

  // --- bias + softmax (rows = pixels; reduce over 16 tx lanes) ---
#pragma unroll
  for (int i = 0; i < 4; ++i) {
    int pp = ty * 4 + i;
    float m_ = -1e30f;
#pragma unroll
    for (int qk = 0; qk < 4; ++qk) {
      int hk = qk * 4 + (tx >> 2);
      float gh = rhw[pp * 32 + hk];
#pragma unroll
      for (int j = 0; j < 4; ++j) {
        int wk = (tx * 4 + j) & 15;
        float v = (L[i][qk * 4 + j] + gh + rhw[pp * 32 + 16 + wk]) * 0.125f;
        L[i][qk * 4 + j] = v;
        m_ = fmaxf(m_, v);
      }
    }
    m_ = fmaxf(m_, __shfl_xor(m_, 1));
    m_ = fmaxf(m_, __shfl_xor(m_, 2));
    m_ = fmaxf(m_, __shfl_xor(m_, 4));
    m_ = fmaxf(m_, __shfl_xor(m_, 8));
    float s_ = 0.f;
#pragma unroll
    for (int k2 = 0; k2 < 16; ++k2) {
      float e = __expf(L[i][k2] - m_);
      L[i][k2] = e;
      s_ += e;
    }
    s_ += __shfl_xor(s_, 1);
    s_ += __shfl_xor(s_, 2);
    s_ += __shfl_xor(s_, 4);
    s_ += __shfl_xor(s_, 8);
    float inv = 1.f / s_;
#pragma unroll
    for (int k2 = 0; k2 < 16; ++k2) L[i][k2] *= inv;
  }

  // --- attn probs store: lanes 0-15 = consecutive key-float4s -> full 64B lines ---
#pragma unroll
  for (int i = 0; i < 4; ++i) {
    float* arow = attn_o + ((size_t)bh * HW + pix0 + ty * 4 + i) * 256 + tx * 4;
#pragma unroll
    for (int qk = 0; qk < 4; ++qk) {
      float4 o;
      o.x = L[i][qk * 4 + 0]; o.y = L[i][qk * 4 + 1];
      o.z = L[i][qk * 4 + 2]; o.w = L[i][qk * 4 + 3];
      *(float4*)(arow + qk * 64) = o;
    }
  }

  // --- GEMM2: O = P @ V via P-transpose in LDS ---
  // P_c[key][col'] with col' = ((pix&3)<<4)|(pix>>2), row stride 65:
  //   write bank = (4tx + ty + const) mod 32 -> 2-way (free); read: 16 consecutive banks.
  float acc2[4][4] = {};
#pragma unroll
  for (int qk = 0; qk < 4; ++qk) {
    __syncthreads();  // previous chunk consumed; also retires Qs (u1) on first iter
#pragma unroll
    for (int i = 0; i < 4; ++i) {  // stage Vs_c[cell][d]: straight 16KB copy, coalesced
      int idx = i * 256 + t;
      *(float4*)&u2[idx * 4] = *(const float4*)(vp + kvb + (size_t)qk * 4096 + idx * 4);
    }
#pragma unroll
    for (int i = 0; i < 4; ++i)    // P_c write (GEMM1 roles: ty=pix-group, tx=key-group)
#pragma unroll
      for (int j = 0; j < 4; ++j)
        u1[(tx * 4 + j) * 65 + i * 16 + ty] = L[i][qk * 4 + j];
    __syncthreads();
#pragma unroll 8
    for (int kk = 0; kk < 64; ++kk) {
      // GEMM2 roles: ty=d-group (V broadcast), tx=pix-group (P: 16 consecutive banks)
      float4 vv = *(const float4*)&u2[kk * 64 + ty * 4];
      float va[4] = {vv.x, vv.y, vv.z, vv.w};
      float pa[4];
#pragma unroll
      for (int i = 0; i < 4; ++i) pa[i] = u1[kk * 65 + i * 16 + tx];
#pragma unroll
      for (int dd = 0; dd < 4; ++dd)
#pragma unroll
        for (int i = 0; i < 4; ++i) acc2[dd][i] += pa[i] * va[dd];
    }
  }

  // --- ao store: float4 over 4 consecutive pixels, lanes 0-15 contiguous 256B ---
#pragma unroll
  for (int dd = 0; dd < 4; ++dd) {
    int ch = (ty * 4 + dd) * 4 + head;
    float4 o;
    o.x = acc2[dd][0]; o.y = acc2[dd][1]; o.z = acc2[dd][2]; o.w = acc2[dd][3];
    *(float4*)(ao + ((size_t)b * CH + ch) * HW + pix0 + tx * 4) = o;
  }
}

extern "C" void kernel_launch(void* const* d_in, const int* in_sizes, int n_in,
                              void* d_out, int out_size, void* d_ws, size_t ws_size,
                              hipStream_t stream) {
  const float* x   = (const float*)d_in[0];
  const float* dw1 = (const float*)d_in[1];
  const float* pw1 = (const float*)d_in[2];
  const float* krw = (const float*)d_in[3];
  const float* krh = (const float*)d_in[4];
  const float* dw2 = (const float*)d_in[5];
  const float* pw2 = (const float*)d_in[6];

  float* out = (float*)d_out;                      // [B][256][HW], 16,777,216
  float* attnbuf = out + (size_t)16777216;         // [B*4][HW][256], 67,108,864

  // scratch inside d_out's attn region (dead until k_attn writes it):
  float* t1    = attnbuf;                          // dw1 out          (16.7M)
  float* kfull = attnbuf + (size_t)16777216;       // k full-res       (16.7M)
  float* vfull = attnbuf + (size_t)33554432;       // v full-res       (16.7M)
  // d_ws (f32): q/t2 (16,777,216) + kp (262,144) + vp (262,144)
  float* qb = (float*)d_ws;
  float* kp = qb + (size_t)16777216;               // [bh][64 d][256 cell]
  float* vp = kp + (size_t)262144;                 // [bh][256 cell][64 d]
  float* t2 = qb;                                  // reuse q region after attn

  dim3 b256(256);
  k_dw<<<dim3(1024), b256, 0, stream>>>(x, dw1, t1);
  // fused q/k/v pointwise: M=768 -> grid y=6; y>>1 selects {q,k,v} buffer
  k_pw<<<dim3(128, 6, 4), b256, 0, stream>>>(t1, pw1, qb, kfull, vfull);
  k_poolT<<<dim3(1024), b256, 0, stream>>>(kfull, kp);
  k_pool<<<dim3(1024), b256, 0, stream>>>(vfull, vp);
  k_attn<<<dim3(256, 4, 4), b256, 0, stream>>>(qb, kp, vp, krh, krw, attnbuf, out);
  k_dw<<<dim3(1024), b256, 0, stream>>>(out, dw2, t2);
  k_pw<<<dim3(128, 2, 4), b256, 0, stream>>>(t2, pw2, out, out, out);
}